// Round 7
// baseline (221.716 us; speedup 1.0000x reference)
//
#include <hip/hip_runtime.h>
#include <hip/hip_bf16.h>

#define NF 50
#define NFP 52            // fields padded to 13 groups of 4
#define NG 13
#define NCARD 10000
#define FD 64
#define FROW 72           // f16 per LDS row (144 B stride)

typedef _Float16 h16x8 __attribute__((ext_vector_type(8)));
typedef float f32x4 __attribute__((ext_vector_type(4)));

// One wave per batch element. 64-thread blocks, single kernel node.
__global__ __launch_bounds__(64) void afm_main(
    const int* __restrict__ x,
    const float* __restrict__ emb,
    const float* __restrict__ W1,
    const float* __restrict__ b1,
    const float* __restrict__ w2,
    const float* __restrict__ lin_w,
    const float* __restrict__ lin_b,
    float* __restrict__ out)
{
    __shared__ __align__(16) _Float16 fach[NFP * FROW]; // 7488 B -> 8+ blocks/CU

    const int b    = blockIdx.x;
    const int lane = threadIdx.x;   // 0..63
    const int n16  = lane & 15;
    const int quad = lane >> 4;

    // ---- issue scattered lin_w gather NOW; reduce at the end ----
    float linv = 0.f;
    if (lane < NF)
        linv = lin_w[x[b * NF + lane] + lane * NCARD];

    // ---- stage 52 factor rows as f16 (rows >= NF zero) ----
    for (int t = lane; t < NFP * 8; t += 64) {
        int f = t >> 3, q = t & 7;
        h16x8 h = {0, 0, 0, 0, 0, 0, 0, 0};
        if (f < NF) {
            int gid = x[b * NF + f] + f * NCARD;
            const float* src = emb + (size_t)gid * FD + q * 8;
            float4 v0 = *(const float4*)(src);
            float4 v1 = *(const float4*)(src + 4);
            h[0] = (_Float16)v0.x; h[1] = (_Float16)v0.y;
            h[2] = (_Float16)v0.z; h[3] = (_Float16)v0.w;
            h[4] = (_Float16)v1.x; h[5] = (_Float16)v1.y;
            h[6] = (_Float16)v1.z; h[7] = (_Float16)v1.w;
        }
        *(h16x8*)(fach + (size_t)f * FROW + q * 8) = h;
    }

    // ---- per-lane constants: W1^T A-fragments from L2-hot W1 ----
    h16x8 afragW[8];                       // [mt*2+ks]; A[m=mt*16+n16][k=ks*32+quad*8+jj]
    #pragma unroll
    for (int mt = 0; mt < 4; ++mt)
        #pragma unroll
        for (int ks = 0; ks < 2; ++ks) {
            h16x8 v;
            #pragma unroll
            for (int jj = 0; jj < 8; ++jj)
                v[jj] = (_Float16)W1[(ks * 32 + quad * 8 + jj) * 64 + mt * 16 + n16];
            afragW[mt * 2 + ks] = v;
        }
    h16x8 aones = {(_Float16)1, (_Float16)1, (_Float16)1, (_Float16)1,
                   (_Float16)1, (_Float16)1, (_Float16)1, (_Float16)1};
    f32x4 b1v[4], w2v[4];                  // C row = mt*16 + quad*4 + r
    #pragma unroll
    for (int mt = 0; mt < 4; ++mt) {
        const float4 bb = *(const float4*)(b1 + mt * 16 + quad * 4);
        const float4 ww = *(const float4*)(w2 + mt * 16 + quad * 4);
        b1v[mt] = (f32x4){bb.x, bb.y, bb.z, bb.w};
        w2v[mt] = (f32x4){ww.x, ww.y, ww.z, ww.w};
    }
    __syncthreads();                       // single-wave block: cheap, orders LDS

    // ---- all 91 4x4-group tiles, one wave ----
    const int a4 = n16 >> 2, b4 = n16 & 3;
    float se = 0.f, sei = 0.f;

    for (int gi = 0; gi < NG; ++gi) {
        const int i = gi * 4 + a4;
        const _Float16* ri = fach + (size_t)i * FROW + quad * 8;
        const h16x8 ri0 = *(const h16x8*)(ri);        // i-row register-cached over gj
        const h16x8 ri1 = *(const h16x8*)(ri + 32);

        const _Float16* rjp = fach + (size_t)(gi * 4 + b4) * FROW + quad * 8;
        h16x8 nj0 = *(const h16x8*)(rjp);             // prefetched j-row
        h16x8 nj1 = *(const h16x8*)(rjp + 32);

        for (int gj = gi; gj < NG; ++gj) {
            h16x8 rj0 = nj0, rj1 = nj1;
            if (gj + 1 < NG) {                         // prefetch next j-row
                rjp += 4 * FROW;
                nj0 = *(const h16x8*)(rjp);
                nj1 = *(const h16x8*)(rjp + 32);
            }
            h16x8 pr0 = ri0 * rj0;                    // v_pk_mul_f16 x4 each
            h16x8 pr1 = ri1 * rj1;

            f32x4 accS = __builtin_amdgcn_mfma_f32_16x16x32_f16(aones, pr0, (f32x4){0.f, 0.f, 0.f, 0.f}, 0, 0, 0);
            accS = __builtin_amdgcn_mfma_f32_16x16x32_f16(aones, pr1, accS, 0, 0, 0);
            // accS[*] = inter_sum(pair column n16) in every lane

            float lp[4];                               // independent partials
            #pragma unroll
            for (int mt = 0; mt < 4; ++mt) {
                f32x4 acc = __builtin_amdgcn_mfma_f32_16x16x32_f16(afragW[mt * 2 + 0], pr0, b1v[mt], 0, 0, 0);
                acc = __builtin_amdgcn_mfma_f32_16x16x32_f16(afragW[mt * 2 + 1], pr1, acc, 0, 0, 0);
                float s0 = fmaxf(acc[0], 0.f) * w2v[mt][0] + fmaxf(acc[1], 0.f) * w2v[mt][1];
                float s1 = fmaxf(acc[2], 0.f) * w2v[mt][2] + fmaxf(acc[3], 0.f) * w2v[mt][3];
                lp[mt] = s0 + s1;
            }
            float lacc = (lp[0] + lp[1]) + (lp[2] + lp[3]);
            lacc += __shfl_xor(lacc, 16, 64);          // att rows live across quads
            lacc += __shfl_xor(lacc, 32, 64);

            const int j = gj * 4 + b4;
            const bool valid = (i < j) && (j < NF);
            float e = valid ? __expf(lacc) : 0.f;      // logits O(1): no max needed
            se  += e;
            sei += e * accS[0];
        }
    }

    // reduce over the 16 pair-residues (quads hold identical copies)
    #pragma unroll
    for (int d = 1; d <= 8; d <<= 1) {
        se  += __shfl_xor(se, d, 64);
        sei += __shfl_xor(sei, d, 64);
    }
    // linear term (loads issued at kernel start have long since landed)
    #pragma unroll
    for (int d = 1; d <= 32; d <<= 1) linv += __shfl_xor(linv, d, 64);

    if (lane == 0)
        out[b] = linv + lin_b[0] + sei / se;
}

extern "C" void kernel_launch(void* const* d_in, const int* in_sizes, int n_in,
                              void* d_out, int out_size, void* d_ws, size_t ws_size,
                              hipStream_t stream) {
    const int*   x     = (const int*)d_in[0];
    const float* emb   = (const float*)d_in[1];
    const float* W1    = (const float*)d_in[2];
    const float* b1    = (const float*)d_in[3];
    const float* w2    = (const float*)d_in[4];
    // d_in[5] = b2 : constant shift on logits, cancels in softmax
    const float* lin_w = (const float*)d_in[6];
    const float* lin_b = (const float*)d_in[7];
    float* out = (float*)d_out;
    const int batch = out_size; // 2048
    afm_main<<<batch, 64, 0, stream>>>(x, emb, W1, b1, w2, lin_w, lin_b, out);
}